// Round 5
// baseline (402.869 us; speedup 1.0000x reference)
//
#include <hip/hip_runtime.h>
#include <stdint.h>

// ---------------------------------------------------------------------------
// CrossAttention2D on MI355X (gfx950)  — round 5 (= round-4 source, resubmitted
// after GPU acquisition timeout; no bench data to act on).
// B=4, C=D=256, H=W=64, N=4096. fp32 in/out.
// attn: KVBLK=64, counted-vmcnt software pipeline (raw s_barrier, loads in
// flight across barriers), per-wave LDS P-tile (no shuffles), log2 softmax.
// proj: full-column blocks (X staged once for all 256 output channels).
// ---------------------------------------------------------------------------

#define NB 4
#define CC 256
#define DD 256
#define NN 4096
#define PS (NB * NN * DD)

typedef float f32x4 __attribute__((ext_vector_type(4)));
typedef unsigned int u32x4 __attribute__((ext_vector_type(4)));
typedef unsigned int u32x2 __attribute__((ext_vector_type(2)));
typedef _Float16 f16x8 __attribute__((ext_vector_type(8)));
typedef __fp16 fp16x2 __attribute__((ext_vector_type(2)));  // cvt_pkrtz native type

#define MFMAH(a, b, c) __builtin_amdgcn_mfma_f32_16x16x32_f16((a), (b), (c), 0, 0, 0)

__device__ __forceinline__ uint16_t h2u(_Float16 h) {
    return __builtin_bit_cast(unsigned short, h);
}
__device__ __forceinline__ uint32_t packh(_Float16 a, _Float16 b) {
    return (uint32_t)h2u(a) | ((uint32_t)h2u(b) << 16);
}
__device__ __forceinline__ f16x8 ldsh8(const void* p) {
    return __builtin_bit_cast(f16x8, *(const u32x4*)p);
}
__device__ __forceinline__ void split8h(const float* v, f16x8& hi, f16x8& lo) {
#pragma unroll
    for (int j = 0; j < 8; ++j) {
        _Float16 h = (_Float16)v[j];
        hi[j] = h;
        lo[j] = (_Float16)(v[j] - (float)h);
    }
}

// ---------------------------------------------------------------------------
// Kernel 1: QKV projections + bias + pe -> fp16 planes.
//   proj 0: Q = (Wq*Y + bq + pe) * (1/16 * log2e)  -> Qp [B][N][D]
//   proj 1: K =  Wk*S + bk + pe                    -> Kp [B][N][D]
//   proj 2: V =  Wv*S + bv                         -> Vp [B][D][N]
// grid = 3*4*64 = 768 blocks of 256 threads; 256d x 64n output per block.
// ---------------------------------------------------------------------------
__global__ __launch_bounds__(256) void proj_kernel(
    const float* __restrict__ Y, const float* __restrict__ S,
    const float* __restrict__ Wq, const float* __restrict__ bq,
    const float* __restrict__ Wk, const float* __restrict__ bk,
    const float* __restrict__ Wv, const float* __restrict__ bv,
    uint16_t* __restrict__ Qp, uint16_t* __restrict__ Kp,
    uint16_t* __restrict__ Vp) {
    __shared__ char XsH[64 * 64];   // [n=64][c=32] fp16 hi
    __shared__ char XsL[64 * 64];   // lo plane
    __shared__ float Bz[64 * 68];   // transpose bounce

    int bi = blockIdx.x;
    int proj = bi >> 8;
    int rem = bi & 255;
    int b = rem >> 6;
    int nt = rem & 63;
    int n0 = nt * 64;

    int t = threadIdx.x;
    int lane = t & 63, wv = t >> 6;
    int g = lane >> 4, li = lane & 15;

    const float* X = (proj == 0 ? Y : S) + (size_t)b * CC * NN;
    const float* W = proj == 0 ? Wq : (proj == 1 ? Wk : Wv);
    const float* bias = proj == 0 ? bq : (proj == 1 ? bk : bv);

    f32x4 acc[4][4];  // [dt][nf]
#pragma unroll
    for (int i = 0; i < 4; ++i)
#pragma unroll
        for (int j = 0; j < 4; ++j) acc[i][j] = (f32x4){0.f, 0.f, 0.f, 0.f};

    int nloc = t & 63;
    int cq = t >> 6;
    uint32_t spch = (uint32_t)(cq ^ ((nloc >> 1) & 3));
    uint32_t rpch = (uint32_t)(g ^ ((li >> 1) & 3));

    for (int kk = 0; kk < 8; ++kk) {
        int c0 = kk * 32;
        {
            const float* xp = X + (size_t)(c0 + cq * 8) * NN + n0 + nloc;
            float xv[8];
#pragma unroll
            for (int j = 0; j < 8; ++j) xv[j] = xp[(size_t)j * NN];
            u32x4 hw, lw;
#pragma unroll
            for (int w = 0; w < 4; ++w) {
                float x = xv[2 * w], y = xv[2 * w + 1];
                _Float16 hx = (_Float16)x, hy = (_Float16)y;
                hw[w] = packh(hx, hy);
                lw[w] = packh((_Float16)(x - (float)hx), (_Float16)(y - (float)hy));
            }
            *(u32x4*)(XsH + nloc * 64 + spch * 16) = hw;
            *(u32x4*)(XsL + nloc * 64 + spch * 16) = lw;
        }
        __syncthreads();
        f16x8 xh[4], xl[4];
#pragma unroll
        for (int nf = 0; nf < 4; ++nf) {
            xh[nf] = ldsh8(XsH + (nf * 16 + li) * 64 + rpch * 16);
            xl[nf] = ldsh8(XsL + (nf * 16 + li) * 64 + rpch * 16);
        }
#pragma unroll
        for (int dt = 0; dt < 4; ++dt) {
            const float* wr =
                W + (size_t)(dt * 64 + wv * 16 + li) * CC + c0 + g * 8;
            float wvv[8];
            *(float4*)&wvv[0] = ((const float4*)wr)[0];
            *(float4*)&wvv[4] = ((const float4*)wr)[1];
            f16x8 wh, wl;
            split8h(wvv, wh, wl);
#pragma unroll
            for (int nf = 0; nf < 4; ++nf) {
                acc[dt][nf] = MFMAH(wh, xh[nf], acc[dt][nf]);
                acc[dt][nf] = MFMAH(wh, xl[nf], acc[dt][nf]);
                acc[dt][nf] = MFMAH(wl, xh[nf], acc[dt][nf]);
            }
        }
        __syncthreads();
    }

    if (proj == 2) {
#pragma unroll
        for (int dt = 0; dt < 4; ++dt) {
#pragma unroll
            for (int r = 0; r < 4; ++r) {
                int d = dt * 64 + wv * 16 + g * 4 + r;
                float bs = bias[d];
#pragma unroll
                for (int nf = 0; nf < 4; ++nf) {
                    int n = n0 + nf * 16 + li;
                    float v = acc[dt][nf][r] + bs;
                    Vp[(size_t)(b * DD + d) * NN + n] = h2u((_Float16)v);
                }
            }
        }
    } else {
        const float QSCALE = 0.0625f * 1.4426950408889634f;  // 1/16 * log2e
#pragma unroll 1
        for (int dt = 0; dt < 4; ++dt) {
            if (dt) __syncthreads();
#pragma unroll
            for (int r = 0; r < 4; ++r) {
                int d = dt * 64 + wv * 16 + g * 4 + r;
                float bs = bias[d];
                int jj = d & 63;
                float inv = exp2f((float)jj * -0.20762050593046f);  // 10000^(-jj/64)
#pragma unroll
                for (int nf = 0; nf < 4; ++nf) {
                    int n = n0 + nf * 16 + li;
                    float v = acc[dt][nf][r] + bs;
                    float pos = (d < 128) ? (float)(n & 63) : (float)(n >> 6);
                    float ar = pos * inv;
                    v += (d & 64) ? cosf(ar) : sinf(ar);
                    if (proj == 0) v *= QSCALE;
                    Bz[(nf * 16 + li) * 68 + wv * 16 + g * 4 + r] = v;
                }
            }
            __syncthreads();
            {
                int nl = t >> 2;
                int dk = (t & 3) * 16;
                float vv[16];
#pragma unroll
                for (int q = 0; q < 4; ++q)
                    *(float4*)&vv[q * 4] = *(const float4*)&Bz[nl * 68 + dk + q * 4];
                u32x4 w0, w1;
#pragma unroll
                for (int w = 0; w < 4; ++w)
                    w0[w] = packh((_Float16)vv[2 * w], (_Float16)vv[2 * w + 1]);
#pragma unroll
                for (int w = 0; w < 4; ++w)
                    w1[w] = packh((_Float16)vv[8 + 2 * w], (_Float16)vv[9 + 2 * w]);
                uint16_t* Ph = (proj == 0) ? Qp : Kp;
                size_t o = (size_t)(b * NN + n0 + nl) * DD + dt * 64 + dk;
                ((u32x4*)(Ph + o))[0] = w0;
                ((u32x4*)(Ph + o))[1] = w1;
            }
        }
    }
}

// ---------------------------------------------------------------------------
// Kernel 2: flash attention (swapped QK^T, log2 domain) + fused out-proj.
// grid = 256 (XCD-swizzled), 256 thr (4 waves x 16 q-rows), KVBLK=64.
// LDS 144KB: two 64KB KV buffers (K 32KB | V 32KB) + 16KB per-wave P scratch.
// Counted vmcnt(16): next tile's 16 global_load_lds stay in flight across
// the barrier; raw s_barrier (no implicit vmcnt(0) drain).
// ---------------------------------------------------------------------------
__global__ __launch_bounds__(256, 1) void attn_kernel(
    const uint16_t* __restrict__ Qp, const uint16_t* __restrict__ Kp,
    const uint16_t* __restrict__ Vp,
    const float* __restrict__ Wo, const float* __restrict__ bo,
    float* __restrict__ Out) {
    extern __shared__ char smem[];

    int t = threadIdx.x;
    int lane = t & 63, wv = t >> 6;
    int g = lane >> 4, li = lane & 15;

    int orig = ((blockIdx.x & 7) << 5) + (blockIdx.x >> 3);
    int b = orig >> 6;
    int nt = orig & 63;
    int n0 = nt * 64;

    // ---- Q fragments (B-operand: col n = li, k = g*8.. within kf*32)
    f16x8 qh[8];
    {
        size_t qrow = (size_t)(b * NN + n0 + wv * 16 + li) * DD;
#pragma unroll
        for (int kf = 0; kf < 8; ++kf)
            qh[kf] =
                __builtin_bit_cast(f16x8, *(const u32x4*)(Qp + qrow + kf * 32 + g * 8));
    }

    // ---- staging: w0: K m0-31, w1: K m32-63, w2: V d0-127, w3: V d128-255.
    const uint16_t* splane;
    uint32_t dstbase, adv;
    uint32_t soff[16];
    if (wv < 2) {
        splane = Kp + (size_t)b * NN * DD;
        dstbase = (uint32_t)wv * 16384u;
        adv = 64 * 256;
#pragma unroll
        for (int i = 0; i < 16; ++i) {
            int rr = wv * 32 + 2 * i + (lane >> 5);
            int cc = lane & 31;
            soff[i] = (uint32_t)(rr * 256 + ((cc ^ (rr & 7)) * 8));
        }
    } else {
        splane = Vp + (size_t)b * DD * NN;
        dstbase = 32768u + (uint32_t)(wv - 2) * 16384u;
        adv = 64;
#pragma unroll
        for (int i = 0; i < 16; ++i) {
            int rr = (wv - 2) * 128 + i * 8 + (lane >> 3);
            int cc = lane & 7;
            soff[i] = (uint32_t)rr * 4096u + (uint32_t)((cc ^ (rr & 7)) * 8);
        }
    }

    f32x4 acc[16];  // O^T: col n = li, row d = df*16 + g*4 + r
#pragma unroll
    for (int i = 0; i < 16; ++i) acc[i] = (f32x4){0.f, 0.f, 0.f, 0.f};
    float mrun = -__builtin_inff();
    float lrun = 0.f;

#define STAGE(tt, sb)                                                                   \
    do {                                                                                \
        uint32_t mo = (uint32_t)(tt)*adv;                                               \
        char* db = smem + (sb)*65536 + dstbase;                                         \
        _Pragma("unroll") for (int i = 0; i < 16; ++i) {                                \
            __builtin_amdgcn_global_load_lds(                                           \
                (const __attribute__((address_space(1))) unsigned int*)(splane +        \
                                                                        soff[i] + mo),  \
                (__attribute__((address_space(3))) unsigned int*)(db + i * 1024), 16, 0,\
                0);                                                                     \
        }                                                                               \
    } while (0)

    STAGE(0, 0);

    uint32_t PB = 131072u + (uint32_t)wv * 4096u;  // per-wave P scratch

#pragma unroll 1
    for (int tt = 0; tt < 64; ++tt) {
        uint32_t sbase = (tt & 1) ? 65536u : 0u;
        if (tt < 63) {
            STAGE(tt + 1, (tt + 1) & 1);
            asm volatile("s_waitcnt vmcnt(16)" ::: "memory");
        } else {
            asm volatile("s_waitcnt vmcnt(0)" ::: "memory");
        }
        __builtin_amdgcn_s_barrier();

        // ---- QK: S^T = K*Q  (A = K rows m, B = Q cols n), 4 chains
        f32x4 st[4];
#pragma unroll
        for (int mf = 0; mf < 4; ++mf) st[mf] = (f32x4){0.f, 0.f, 0.f, 0.f};
        __builtin_amdgcn_s_setprio(1);
#pragma unroll
        for (int kf = 0; kf < 8; ++kf) {
            uint32_t cof = (uint32_t)(((kf * 4 + g) ^ (li & 7)) * 16);
#pragma unroll
            for (int mf = 0; mf < 4; ++mf) {
                f16x8 kfr = ldsh8(smem + sbase + (uint32_t)(mf * 16 + li) * 512 + cof);
                st[mf] = MFMAH(kfr, qh[kf], st[mf]);
            }
        }
        __builtin_amdgcn_s_setprio(0);

        // ---- online softmax (log2 domain); lane: q-col li, m = mf*16+g*4+r
        float sv[16];
#pragma unroll
        for (int mf = 0; mf < 4; ++mf)
#pragma unroll
            for (int r = 0; r < 4; ++r) sv[mf * 4 + r] = st[mf][r];
        float pm = sv[0];
#pragma unroll
        for (int j = 1; j < 16; ++j) pm = fmaxf(pm, sv[j]);
        pm = fmaxf(pm, __shfl_xor(pm, 16));
        pm = fmaxf(pm, __shfl_xor(pm, 32));
        if (__any(pm > mrun + 5.77f)) {  // defer-max, log2 units
            float mnew = fmaxf(mrun, pm);
            float fac = exp2f(mrun - mnew);
            lrun *= fac;
#pragma unroll
            for (int i = 0; i < 16; ++i) {
                acc[i][0] *= fac; acc[i][1] *= fac;
                acc[i][2] *= fac; acc[i][3] *= fac;
            }
            mrun = mnew;
        }
        float p[16];
        float ps = 0.f;
#pragma unroll
        for (int j = 0; j < 16; ++j) {
            p[j] = exp2f(sv[j] - mrun);
            ps += p[j];
        }
        ps += __shfl_xor(ps, 16);
        ps += __shfl_xor(ps, 32);
        lrun += ps;

        // ---- pack P pairs to hi/lo fp16 words
        uint32_t hw[8], lw[8];
#pragma unroll
        for (int w = 0; w < 8; ++w) {
            fp16x2 h2 = __builtin_amdgcn_cvt_pkrtz(p[2 * w], p[2 * w + 1]);
            hw[w] = __builtin_bit_cast(uint32_t, h2);
            float r0 = p[2 * w] - (float)h2[0];
            float r1 = p[2 * w + 1] - (float)h2[1];
            lw[w] = __builtin_bit_cast(uint32_t, __builtin_amdgcn_cvt_pkrtz(r0, r1));
        }
        // ---- store P^T tile [16 n][64 m] fp16 to per-wave LDS (swizzled)
        {
            uint32_t sub = (uint32_t)((g & 1) * 8);
#pragma unroll
            for (int mf = 0; mf < 4; ++mf) {
                uint32_t a = PB + (uint32_t)li * 128 +
                             (uint32_t)((((2 * mf + (g >> 1)) ^ (li & 7))) * 16) + sub;
                *(u32x2*)(smem + a) = (u32x2){hw[2 * mf], hw[2 * mf + 1]};
                *(u32x2*)(smem + a + 2048) = (u32x2){lw[2 * mf], lw[2 * mf + 1]};
            }
        }
        // ---- read P B-fragments (k = m)
        f16x8 pbh[2], pbl[2];
#pragma unroll
        for (int kf2 = 0; kf2 < 2; ++kf2) {
            uint32_t a = PB + (uint32_t)li * 128 +
                         (uint32_t)(((kf2 * 4 + g) ^ (li & 7)) * 16);
            pbh[kf2] = ldsh8(smem + a);
            pbl[kf2] = ldsh8(smem + a + 2048);
        }

        // ---- PV: O^T += V^T * P  (A = V^T rows d)
        __builtin_amdgcn_s_setprio(1);
#pragma unroll
        for (int df = 0; df < 16; ++df) {
            uint32_t vb = sbase + 32768u + (uint32_t)(df * 16 + li) * 128;
            f16x8 v0 = ldsh8(smem + vb + (uint32_t)(((g) ^ (li & 7)) * 16));
            f16x8 v1 = ldsh8(smem + vb + (uint32_t)(((4 + g) ^ (li & 7)) * 16));
            acc[df] = MFMAH(v0, pbh[0], acc[df]);
            acc[df] = MFMAH(v0, pbl[0], acc[df]);
            acc[df] = MFMAH(v1, pbh[1], acc[df]);
            acc[df] = MFMAH(v1, pbl[1], acc[df]);
        }
        __builtin_amdgcn_s_setprio(0);
        asm volatile("s_waitcnt lgkmcnt(0)" ::: "memory");
        __builtin_amdgcn_s_barrier();
    }
#undef STAGE

    // ---- normalize, bounce O^T -> LDS fp16 hi/lo [64 n][256 d] swizzled
    float rl = 1.0f / lrun;
    char* zh = smem;
    char* zl = smem + 32768;
    {
        int n = wv * 16 + li;
#pragma unroll
        for (int df = 0; df < 16; ++df) {
#pragma unroll
            for (int rp = 0; rp < 2; ++rp) {
                float a0 = acc[df][2 * rp] * rl, a1 = acc[df][2 * rp + 1] * rl;
                _Float16 h0 = (_Float16)a0, h1 = (_Float16)a1;
                uint32_t whi = packh(h0, h1);
                uint32_t wlo =
                    packh((_Float16)(a0 - (float)h0), (_Float16)(a1 - (float)h1));
                uint32_t chunk = (uint32_t)((df * 2 + (g >> 1)) ^ (li & 7));
                uint32_t off = (uint32_t)n * 512 + chunk * 16 + (g & 1) * 8 + rp * 4;
                *(uint32_t*)(zh + off) = whi;
                *(uint32_t*)(zl + off) = wlo;
            }
        }
    }
    __syncthreads();

    // ---- fused output projection: out[cs][n-tile] = Wo * Z^T + bo
    f32x4 oc[4][4];
#pragma unroll
    for (int i = 0; i < 4; ++i)
#pragma unroll
        for (int j = 0; j < 4; ++j) oc[i][j] = (f32x4){0.f, 0.f, 0.f, 0.f};
    int cs0 = wv * 64;
#pragma unroll 1
    for (int kf = 0; kf < 8; ++kf) {
        f16x8 zhv[4], zlv[4];
#pragma unroll
        for (int nf = 0; nf < 4; ++nf) {
            uint32_t off = (uint32_t)(nf * 16 + li) * 512 +
                           (uint32_t)((kf * 4 + g) ^ (li & 7)) * 16;
            zhv[nf] = ldsh8(zh + off);
            zlv[nf] = ldsh8(zl + off);
        }
#pragma unroll
        for (int csf = 0; csf < 4; ++csf) {
            const float* wr = Wo + (size_t)(cs0 + csf * 16 + li) * DD + kf * 32 + g * 8;
            float wvv[8];
            *(float4*)&wvv[0] = ((const float4*)wr)[0];
            *(float4*)&wvv[4] = ((const float4*)wr)[1];
            f16x8 wh, wl;
            split8h(wvv, wh, wl);
#pragma unroll
            for (int nf = 0; nf < 4; ++nf) {
                oc[csf][nf] = MFMAH(wh, zhv[nf], oc[csf][nf]);
                oc[csf][nf] = MFMAH(wh, zlv[nf], oc[csf][nf]);
                oc[csf][nf] = MFMAH(wl, zhv[nf], oc[csf][nf]);
            }
        }
    }
#pragma unroll
    for (int csf = 0; csf < 4; ++csf) {
#pragma unroll
        for (int r = 0; r < 4; ++r) {
            int cs = cs0 + csf * 16 + g * 4 + r;
            float bb = bo[cs];
#pragma unroll
            for (int nf = 0; nf < 4; ++nf)
                Out[(size_t)(b * 256 + cs) * NN + n0 + nf * 16 + li] =
                    oc[csf][nf][r] + bb;
        }
    }
}

// ---------------------------------------------------------------------------
extern "C" void kernel_launch(void* const* d_in, const int* in_sizes, int n_in,
                              void* d_out, int out_size, void* d_ws, size_t ws_size,
                              hipStream_t stream) {
    (void)in_sizes; (void)n_in; (void)out_size; (void)ws_size;
    const float* Y = (const float*)d_in[0];
    const float* S = (const float*)d_in[1];
    const float* Wq = (const float*)d_in[2];
    const float* bq = (const float*)d_in[3];
    const float* Wk = (const float*)d_in[4];
    const float* bk = (const float*)d_in[5];
    const float* Wv = (const float*)d_in[6];
    const float* bv = (const float*)d_in[7];
    const float* Wo = (const float*)d_in[8];
    const float* bo = (const float*)d_in[9];
    float* Out = (float*)d_out;

    uint16_t* ws = (uint16_t*)d_ws;
    uint16_t* Qp = ws + 0 * (size_t)PS;
    uint16_t* Kp = ws + 1 * (size_t)PS;
    uint16_t* Vp = ws + 2 * (size_t)PS;

    (void)hipFuncSetAttribute((const void*)attn_kernel,
                              hipFuncAttributeMaxDynamicSharedMemorySize, 147456);

    proj_kernel<<<768, 256, 0, stream>>>(Y, S, Wq, bq, Wk, bk, Wv, bv, Qp, Kp, Vp);
    attn_kernel<<<256, 256, 147456, stream>>>(Qp, Kp, Vp, Wo, bo, Out);
}

// Round 6
// 302.823 us; speedup vs baseline: 1.3304x; 1.3304x over previous
//
#include <hip/hip_runtime.h>
#include <stdint.h>

// ---------------------------------------------------------------------------
// CrossAttention2D on MI355X (gfx950)  — round 6
// B=4, C=D=256, H=W=64, N=4096. fp32 in/out.
// proj: reverted to round-2 structure (measured 85us), Q scale folds log2e.
// attn: deferred-softmax pipeline — iter t runs QK(t) || SM+PV(t-1) so the
// softmax serial chain hides under MFMA/LDS. K staged 2 ahead (2 slots),
// V staged 1 ahead (2 slots), P single-plane per-wave LDS tile, all LDS
// addresses hoisted to registers + imm offsets. LDS 136KB.
// ---------------------------------------------------------------------------

#define NB 4
#define CC 256
#define DD 256
#define NN 4096
#define PS (NB * NN * DD)

typedef float f32x4 __attribute__((ext_vector_type(4)));
typedef unsigned int u32x4 __attribute__((ext_vector_type(4)));
typedef unsigned int u32x2 __attribute__((ext_vector_type(2)));
typedef _Float16 f16x8 __attribute__((ext_vector_type(8)));
typedef __fp16 fp16x2 __attribute__((ext_vector_type(2)));  // cvt_pkrtz native type

#define MFMAH(a, b, c) __builtin_amdgcn_mfma_f32_16x16x32_f16((a), (b), (c), 0, 0, 0)

__device__ __forceinline__ uint16_t h2u(_Float16 h) {
    return __builtin_bit_cast(unsigned short, h);
}
__device__ __forceinline__ uint32_t packh(_Float16 a, _Float16 b) {
    return (uint32_t)h2u(a) | ((uint32_t)h2u(b) << 16);
}
__device__ __forceinline__ f16x8 ldsh8(const void* p) {
    return __builtin_bit_cast(f16x8, *(const u32x4*)p);
}
__device__ __forceinline__ void split8h(const float* v, f16x8& hi, f16x8& lo) {
#pragma unroll
    for (int j = 0; j < 8; ++j) {
        _Float16 h = (_Float16)v[j];
        hi[j] = h;
        lo[j] = (_Float16)(v[j] - (float)h);
    }
}

// ---------------------------------------------------------------------------
// Kernel 1 (round-2 structure, measured 85us): QKV proj + bias + pe -> fp16.
//   proj 0: Q = (Wq*Y + bq + pe) * (1/16 * log2e)  -> Qp [B][N][D]
//   proj 1: K =  Wk*S + bk + pe                    -> Kp [B][N][D]
//   proj 2: V =  Wv*S + bv                         -> Vp [B][D][N]
// grid = 3*4*4*64 = 3072 blocks of 256 threads; 64d x 64n tile each.
// ---------------------------------------------------------------------------
__global__ __launch_bounds__(256) void proj_kernel(
    const float* __restrict__ Y, const float* __restrict__ S,
    const float* __restrict__ Wq, const float* __restrict__ bq,
    const float* __restrict__ Wk, const float* __restrict__ bk,
    const float* __restrict__ Wv, const float* __restrict__ bv,
    uint16_t* __restrict__ Qp, uint16_t* __restrict__ Kp,
    uint16_t* __restrict__ Vp) {
    __shared__ char XsH[64 * 64];   // [n=64][c=32] fp16 hi
    __shared__ char XsL[64 * 64];   // lo plane
    __shared__ float Bz[64 * 68];   // transpose bounce

    int bi = blockIdx.x;
    int proj = bi >> 10;
    int rem = bi & 1023;
    int b = rem >> 8;
    int dt = (rem >> 6) & 3;
    int nt = rem & 63;
    int d0 = dt * 64, n0 = nt * 64;

    int t = threadIdx.x;
    int lane = t & 63, wv = t >> 6;
    int g = lane >> 4, li = lane & 15;

    const float* X = (proj == 0 ? Y : S) + (size_t)b * CC * NN;
    const float* W = proj == 0 ? Wq : (proj == 1 ? Wk : Wv);
    const float* bias = proj == 0 ? bq : (proj == 1 ? bk : bv);

    f32x4 acc[4];
#pragma unroll
    for (int i = 0; i < 4; ++i) acc[i] = (f32x4){0.f, 0.f, 0.f, 0.f};

    int nloc = t & 63;
    int cq = t >> 6;
    uint32_t spch = (uint32_t)(cq ^ ((nloc >> 1) & 3));
    uint32_t rpch = (uint32_t)(g ^ ((li >> 1) & 3));

    for (int kk = 0; kk < 8; ++kk) {
        int c0 = kk * 32;
        {
            const float* xp = X + (size_t)(c0 + cq * 8) * NN + n0 + nloc;
            float xv[8];
#pragma unroll
            for (int j = 0; j < 8; ++j) xv[j] = xp[(size_t)j * NN];
            u32x4 hw, lw;
#pragma unroll
            for (int w = 0; w < 4; ++w) {
                float x = xv[2 * w], y = xv[2 * w + 1];
                _Float16 hx = (_Float16)x, hy = (_Float16)y;
                hw[w] = packh(hx, hy);
                lw[w] = packh((_Float16)(x - (float)hx), (_Float16)(y - (float)hy));
            }
            *(u32x4*)(XsH + nloc * 64 + spch * 16) = hw;
            *(u32x4*)(XsL + nloc * 64 + spch * 16) = lw;
        }
        __syncthreads();
        const float* wr = W + (size_t)(d0 + wv * 16 + li) * CC + c0 + g * 8;
        float wvv[8];
        *(float4*)&wvv[0] = ((const float4*)wr)[0];
        *(float4*)&wvv[4] = ((const float4*)wr)[1];
        f16x8 wh, wl;
        split8h(wvv, wh, wl);
#pragma unroll
        for (int nf = 0; nf < 4; ++nf) {
            const char* bp = XsH + (nf * 16 + li) * 64 + rpch * 16;
            f16x8 xh = ldsh8(bp);
            f16x8 xl = ldsh8(XsL + (nf * 16 + li) * 64 + rpch * 16);
            acc[nf] = MFMAH(wh, xh, acc[nf]);
            acc[nf] = MFMAH(wh, xl, acc[nf]);
            acc[nf] = MFMAH(wl, xh, acc[nf]);
        }
        __syncthreads();
    }

    if (proj == 2) {
#pragma unroll
        for (int r = 0; r < 4; ++r) {
            int d = d0 + wv * 16 + g * 4 + r;
            float bs = bias[d];
#pragma unroll
            for (int nf = 0; nf < 4; ++nf) {
                int n = n0 + nf * 16 + li;
                float v = acc[nf][r] + bs;
                Vp[(size_t)(b * DD + d) * NN + n] = h2u((_Float16)v);
            }
        }
    } else {
        const float QSCALE = 0.0625f * 1.4426950408889634f;  // 1/16 * log2e
#pragma unroll
        for (int r = 0; r < 4; ++r) {
            int d = d0 + wv * 16 + g * 4 + r;
            float bs = bias[d];
            int jj = d & 63;
            float inv = exp2f((float)jj * -0.20762050593046f);  // 10000^(-jj/64)
#pragma unroll
            for (int nf = 0; nf < 4; ++nf) {
                int n = n0 + nf * 16 + li;
                float v = acc[nf][r] + bs;
                float pos = (d < 128) ? (float)(n & 63) : (float)(n >> 6);
                float ar = pos * inv;
                v += (d & 64) ? cosf(ar) : sinf(ar);
                if (proj == 0) v *= QSCALE;
                Bz[(nf * 16 + li) * 68 + wv * 16 + g * 4 + r] = v;
            }
        }
        __syncthreads();
        {
            int nl = t >> 2;
            int dk = (t & 3) * 16;
            float vv[16];
#pragma unroll
            for (int q = 0; q < 4; ++q)
                *(float4*)&vv[q * 4] = *(const float4*)&Bz[nl * 68 + dk + q * 4];
            u32x4 w0, w1;
#pragma unroll
            for (int w = 0; w < 4; ++w)
                w0[w] = packh((_Float16)vv[2 * w], (_Float16)vv[2 * w + 1]);
#pragma unroll
            for (int w = 0; w < 4; ++w)
                w1[w] = packh((_Float16)vv[8 + 2 * w], (_Float16)vv[9 + 2 * w]);
            uint16_t* Ph = (proj == 0) ? Qp : Kp;
            size_t o = (size_t)(b * NN + n0 + nl) * DD + d0 + dk;
            ((u32x4*)(Ph + o))[0] = w0;
            ((u32x4*)(Ph + o))[1] = w1;
        }
    }
}

// ---------------------------------------------------------------------------
// Kernel 2: flash attention, deferred-softmax pipeline + fused out-proj.
// grid = 256 (XCD-swizzled), 256 thr (4 waves x 16 q-rows), KVBLK=64.
// LDS 136KB: K slots @0/@32K, V slots @64K/@96K, P @128K (2KB/wave).
// Iter t: [vmcnt(16); barrier; QK(t) from Kslot(t&1); SM+PV(t-1) from
// Vslot((t-1)&1); lgkm; barrier; stage K(t+2) / V(t+1)].
// ---------------------------------------------------------------------------
__global__ __launch_bounds__(256, 1) void attn_kernel(
    const uint16_t* __restrict__ Qp, const uint16_t* __restrict__ Kp,
    const uint16_t* __restrict__ Vp,
    const float* __restrict__ Wo, const float* __restrict__ bo,
    float* __restrict__ Out) {
    extern __shared__ char smem[];

    int t = threadIdx.x;
    int lane = t & 63, wv = t >> 6;
    int g = lane >> 4, li = lane & 15;

    int orig = ((blockIdx.x & 7) << 5) + (blockIdx.x >> 3);
    int b = orig >> 6;
    int nt = orig & 63;
    int n0 = nt * 64;

    // ---- Q fragments (B-operand: col n = li, k = g*8.. within kf*32)
    f16x8 qh[8];
    {
        size_t qrow = (size_t)(b * NN + n0 + wv * 16 + li) * DD;
#pragma unroll
        for (int kf = 0; kf < 8; ++kf)
            qh[kf] =
                __builtin_bit_cast(f16x8, *(const u32x4*)(Qp + qrow + kf * 32 + g * 8));
    }

    // ---- staging: w0/w1 stage K (rows 0-31 / 32-63), w2/w3 stage V
    // (d 0-127 / 128-255). 16 x 1KB loads per wave per tile.
    const uint16_t* splane;
    uint32_t dstbase, adv;
    uint32_t soff[16];
    if (wv < 2) {
        splane = Kp + (size_t)b * NN * DD;
        dstbase = (uint32_t)wv * 16384u;
        adv = 64 * 256;
#pragma unroll
        for (int i = 0; i < 16; ++i) {
            int rr = wv * 32 + 2 * i + (lane >> 5);
            int cc = lane & 31;
            soff[i] = (uint32_t)(rr * 256 + ((cc ^ (rr & 7)) * 8));
        }
    } else {
        splane = Vp + (size_t)b * DD * NN;
        dstbase = 65536u + (uint32_t)(wv - 2) * 16384u;
        adv = 64;
#pragma unroll
        for (int i = 0; i < 16; ++i) {
            int rr = (wv - 2) * 128 + i * 8 + (lane >> 3);
            int cc = lane & 7;
            soff[i] = (uint32_t)rr * 4096u + (uint32_t)((cc ^ (rr & 7)) * 8);
        }
    }

    // ---- hoisted LDS read/write addresses (loop-invariant)
    uint32_t PB = 131072u + (uint32_t)wv * 2048u;  // per-wave P tile (2KB)
    uint32_t ka[8];
#pragma unroll
    for (int kf = 0; kf < 8; ++kf)
        ka[kf] = (uint32_t)li * 512u + (uint32_t)(((kf * 4 + g) ^ (li & 7)) * 16);
    uint32_t va0 = 65536u + (uint32_t)li * 128u + (uint32_t)(((g) ^ (li & 7)) * 16);
    uint32_t va1 = 65536u + (uint32_t)li * 128u + (uint32_t)(((4 + g) ^ (li & 7)) * 16);
    uint32_t pw[4];
#pragma unroll
    for (int mf = 0; mf < 4; ++mf)
        pw[mf] = PB + (uint32_t)li * 128u +
                 (uint32_t)((((2 * mf + (g >> 1))) ^ (li & 7)) * 16) +
                 (uint32_t)((g & 1) * 8);
    uint32_t pr0 = PB + (uint32_t)li * 128u + (uint32_t)(((g) ^ (li & 7)) * 16);
    uint32_t pr1 = PB + (uint32_t)li * 128u + (uint32_t)(((4 + g) ^ (li & 7)) * 16);

    f32x4 acc[16];  // O^T: col n = li, row d = df*16 + g*4 + r
#pragma unroll
    for (int i = 0; i < 16; ++i) acc[i] = (f32x4){0.f, 0.f, 0.f, 0.f};
    float mrun = -__builtin_inff();
    float lrun = 0.f;
    f32x4 stA[4], stB[4];

#define STAGEX(tt)                                                                      \
    do {                                                                                \
        uint32_t mo = (uint32_t)(tt)*adv;                                               \
        char* db = smem + (uint32_t)(((tt)&1) * 32768u) + dstbase;                      \
        _Pragma("unroll") for (int i = 0; i < 16; ++i) {                                \
            __builtin_amdgcn_global_load_lds(                                           \
                (const __attribute__((address_space(1))) unsigned int*)(splane +        \
                                                                        soff[i] + mo),  \
                (__attribute__((address_space(3))) unsigned int*)(db + i * 1024), 16, 0,\
                0);                                                                     \
        }                                                                               \
    } while (0)

#define QKPART(T, SC)                                                                   \
    {                                                                                   \
        _Pragma("unroll") for (int mf = 0; mf < 4; ++mf) SC[mf] =                       \
            (f32x4){0.f, 0.f, 0.f, 0.f};                                                \
        __builtin_amdgcn_s_setprio(1);                                                  \
        _Pragma("unroll") for (int kf = 0; kf < 8; ++kf) {                              \
            _Pragma("unroll") for (int mf = 0; mf < 4; ++mf) {                          \
                f16x8 kfr = ldsh8(smem + ka[kf] +                                       \
                                  (uint32_t)(((T)&1) * 32768u + mf * 8192u));           \
                SC[mf] = MFMAH(kfr, qh[kf], SC[mf]);                                    \
            }                                                                           \
        }                                                                               \
        __builtin_amdgcn_s_setprio(0);                                                  \
    }

#define SMPV(T, SP)                                                                     \
    {                                                                                   \
        float sv[16];                                                                   \
        _Pragma("unroll") for (int mf = 0; mf < 4; ++mf)                                \
            _Pragma("unroll") for (int r = 0; r < 4; ++r) sv[mf * 4 + r] = SP[mf][r];   \
        float pm = sv[0];                                                               \
        _Pragma("unroll") for (int j = 1; j < 16; ++j) pm = fmaxf(pm, sv[j]);           \
        pm = fmaxf(pm, __shfl_xor(pm, 16));                                             \
        pm = fmaxf(pm, __shfl_xor(pm, 32));                                             \
        if (__any(pm > mrun + 5.77f)) {                                                 \
            float mnew = fmaxf(mrun, pm);                                               \
            float fac = exp2f(mrun - mnew);                                             \
            lrun *= fac;                                                                \
            _Pragma("unroll") for (int i2 = 0; i2 < 16; ++i2) {                         \
                acc[i2][0] *= fac; acc[i2][1] *= fac;                                   \
                acc[i2][2] *= fac; acc[i2][3] *= fac;                                   \
            }                                                                           \
            mrun = mnew;                                                                \
        }                                                                               \
        float p[16];                                                                    \
        float ps = 0.f;                                                                 \
        _Pragma("unroll") for (int j = 0; j < 16; ++j) {                                \
            p[j] = exp2f(sv[j] - mrun);                                                 \
            ps += p[j];                                                                 \
        }                                                                               \
        uint32_t hw[8];                                                                 \
        _Pragma("unroll") for (int w = 0; w < 8; ++w) hw[w] = __builtin_bit_cast(       \
            uint32_t, __builtin_amdgcn_cvt_pkrtz(p[2 * w], p[2 * w + 1]));              \
        _Pragma("unroll") for (int mf = 0; mf < 4; ++mf) {                              \
            *(u32x2*)(smem + pw[mf]) = (u32x2){hw[2 * mf], hw[2 * mf + 1]};             \
        }                                                                               \
        ps += __shfl_xor(ps, 16);                                                       \
        ps += __shfl_xor(ps, 32);                                                       \
        lrun += ps;                                                                     \
        f16x8 pbh0 = ldsh8(smem + pr0);                                                 \
        f16x8 pbh1 = ldsh8(smem + pr1);                                                 \
        __builtin_amdgcn_s_setprio(1);                                                  \
        _Pragma("unroll") for (int df = 0; df < 16; ++df) {                             \
            uint32_t vo = (uint32_t)((((T)&1) ? 0u : 32768u) + df * 2048u);             \
            f16x8 v0 = ldsh8(smem + va0 + vo);                                          \
            f16x8 v1 = ldsh8(smem + va1 + vo);                                          \
            acc[df] = MFMAH(v0, pbh0, acc[df]);                                         \
            acc[df] = MFMAH(v1, pbh1, acc[df]);                                         \
        }                                                                               \
        __builtin_amdgcn_s_setprio(0);                                                  \
    }

#define ITER(T, SC, SP, DOSM, VMC)                                                      \
    {                                                                                   \
        asm volatile("s_waitcnt vmcnt(" #VMC ")" ::: "memory");                         \
        __builtin_amdgcn_s_barrier();                                                   \
        QKPART(T, SC);                                                                  \
        if (DOSM) SMPV(T, SP);                                                          \
        asm volatile("s_waitcnt lgkmcnt(0)" ::: "memory");                              \
        __builtin_amdgcn_s_barrier();                                                   \
        if (((T) < 62) && (wv < 2)) STAGEX((T) + 2);                                    \
        if (((T) < 63) && (wv >= 2)) STAGEX((T) + 1);                                   \
    }

    // prologue: K(0),K(1) and V(0)
    if (wv < 2) {
        STAGEX(0);
        STAGEX(1);
    } else {
        STAGEX(0);
    }

    ITER(0, stA, stB, 0, 16);
#pragma unroll 1
    for (int tp = 0; tp < 31; ++tp) {
        ITER(2 * tp + 1, stB, stA, 1, 16);
        ITER(2 * tp + 2, stA, stB, 1, 16);
    }
    ITER(63, stB, stA, 1, 0);
    // epilogue: softmax+PV for tile 63 (V slot (64-1)&1 = 1)
    SMPV(64, stB);

#undef ITER
#undef SMPV
#undef QKPART
#undef STAGEX

    // ---- normalize, bounce O^T -> LDS fp16 hi/lo [64 n][256 d] swizzled
    float rl = 1.0f / lrun;
    char* zh = smem;
    char* zl = smem + 32768;
    {
        int n = wv * 16 + li;
#pragma unroll
        for (int df = 0; df < 16; ++df) {
#pragma unroll
            for (int rp = 0; rp < 2; ++rp) {
                float a0 = acc[df][2 * rp] * rl, a1 = acc[df][2 * rp + 1] * rl;
                _Float16 h0 = (_Float16)a0, h1 = (_Float16)a1;
                uint32_t whi = packh(h0, h1);
                uint32_t wlo =
                    packh((_Float16)(a0 - (float)h0), (_Float16)(a1 - (float)h1));
                uint32_t chunk = (uint32_t)((df * 2 + (g >> 1)) ^ (li & 7));
                uint32_t off = (uint32_t)n * 512 + chunk * 16 + (g & 1) * 8 + rp * 4;
                *(uint32_t*)(zh + off) = whi;
                *(uint32_t*)(zl + off) = wlo;
            }
        }
    }
    __syncthreads();

    // ---- fused output projection: out[cs][n-tile] = Wo * Z^T + bo
    f32x4 oc[4][4];
#pragma unroll
    for (int i = 0; i < 4; ++i)
#pragma unroll
        for (int j = 0; j < 4; ++j) oc[i][j] = (f32x4){0.f, 0.f, 0.f, 0.f};
    int cs0 = wv * 64;
#pragma unroll 1
    for (int kf = 0; kf < 8; ++kf) {
        f16x8 zhv[4], zlv[4];
#pragma unroll
        for (int nf = 0; nf < 4; ++nf) {
            uint32_t off = (uint32_t)(nf * 16 + li) * 512 +
                           (uint32_t)((kf * 4 + g) ^ (li & 7)) * 16;
            zhv[nf] = ldsh8(zh + off);
            zlv[nf] = ldsh8(zl + off);
        }
#pragma unroll
        for (int csf = 0; csf < 4; ++csf) {
            const float* wr = Wo + (size_t)(cs0 + csf * 16 + li) * DD + kf * 32 + g * 8;
            float wvv[8];
            *(float4*)&wvv[0] = ((const float4*)wr)[0];
            *(float4*)&wvv[4] = ((const float4*)wr)[1];
            f16x8 wh, wl;
            split8h(wvv, wh, wl);
#pragma unroll
            for (int nf = 0; nf < 4; ++nf) {
                oc[csf][nf] = MFMAH(wh, zhv[nf], oc[csf][nf]);
                oc[csf][nf] = MFMAH(wh, zlv[nf], oc[csf][nf]);
                oc[csf][nf] = MFMAH(wl, zhv[nf], oc[csf][nf]);
            }
        }
    }
#pragma unroll
    for (int csf = 0; csf < 4; ++csf) {
#pragma unroll
        for (int r = 0; r < 4; ++r) {
            int cs = cs0 + csf * 16 + g * 4 + r;
            float bb = bo[cs];
#pragma unroll
            for (int nf = 0; nf < 4; ++nf)
                Out[(size_t)(b * 256 + cs) * NN + n0 + nf * 16 + li] =
                    oc[csf][nf][r] + bb;
        }
    }
}

// ---------------------------------------------------------------------------
extern "C" void kernel_launch(void* const* d_in, const int* in_sizes, int n_in,
                              void* d_out, int out_size, void* d_ws, size_t ws_size,
                              hipStream_t stream) {
    (void)in_sizes; (void)n_in; (void)out_size; (void)ws_size;
    const float* Y = (const float*)d_in[0];
    const float* S = (const float*)d_in[1];
    const float* Wq = (const float*)d_in[2];
    const float* bq = (const float*)d_in[3];
    const float* Wk = (const float*)d_in[4];
    const float* bk = (const float*)d_in[5];
    const float* Wv = (const float*)d_in[6];
    const float* bv = (const float*)d_in[7];
    const float* Wo = (const float*)d_in[8];
    const float* bo = (const float*)d_in[9];
    float* Out = (float*)d_out;

    uint16_t* ws = (uint16_t*)d_ws;
    uint16_t* Qp = ws + 0 * (size_t)PS;
    uint16_t* Kp = ws + 1 * (size_t)PS;
    uint16_t* Vp = ws + 2 * (size_t)PS;

    (void)hipFuncSetAttribute((const void*)attn_kernel,
                              hipFuncAttributeMaxDynamicSharedMemorySize, 139264);

    proj_kernel<<<3072, 256, 0, stream>>>(Y, S, Wq, bq, Wk, bk, Wv, bv, Qp, Kp, Vp);
    attn_kernel<<<256, 256, 139264, stream>>>(Qp, Kp, Vp, Wo, bo, Out);
}

// Round 7
// 259.114 us; speedup vs baseline: 1.5548x; 1.1687x over previous
//
#include <hip/hip_runtime.h>
#include <stdint.h>

// ---------------------------------------------------------------------------
// CrossAttention2D on MI355X (gfx950)  — round 7
// B=4, C=D=256, H=W=64, N=4096. fp32 in/out.
// attn: 512 thr / 8 waves (2 waves/SIMD TLP). Wave w = (qf=w&3, h=w>>2):
// q-fragment qf, KV m-half h. Independent online softmax per wave over its
// m-half; end-of-loop pair merge (flash-split combine) via LDS. KVBLK=64,
// K staged 2 ahead / V 1 ahead, counted vmcnt(8), raw s_barrier.
// proj: unchanged round-6 (passing).
// ---------------------------------------------------------------------------

#define NB 4
#define CC 256
#define DD 256
#define NN 4096
#define PS (NB * NN * DD)

typedef float f32x4 __attribute__((ext_vector_type(4)));
typedef unsigned int u32x4 __attribute__((ext_vector_type(4)));
typedef unsigned int u32x2 __attribute__((ext_vector_type(2)));
typedef _Float16 f16x8 __attribute__((ext_vector_type(8)));
typedef __fp16 fp16x2 __attribute__((ext_vector_type(2)));

#define MFMAH(a, b, c) __builtin_amdgcn_mfma_f32_16x16x32_f16((a), (b), (c), 0, 0, 0)

__device__ __forceinline__ uint16_t h2u(_Float16 h) {
    return __builtin_bit_cast(unsigned short, h);
}
__device__ __forceinline__ uint32_t packh(_Float16 a, _Float16 b) {
    return (uint32_t)h2u(a) | ((uint32_t)h2u(b) << 16);
}
__device__ __forceinline__ f16x8 ldsh8(const void* p) {
    return __builtin_bit_cast(f16x8, *(const u32x4*)p);
}
__device__ __forceinline__ void split8h(const float* v, f16x8& hi, f16x8& lo) {
#pragma unroll
    for (int j = 0; j < 8; ++j) {
        _Float16 h = (_Float16)v[j];
        hi[j] = h;
        lo[j] = (_Float16)(v[j] - (float)h);
    }
}

// ---------------------------------------------------------------------------
// Kernel 1 (unchanged): QKV proj + bias + pe -> fp16 planes.
// ---------------------------------------------------------------------------
__global__ __launch_bounds__(256) void proj_kernel(
    const float* __restrict__ Y, const float* __restrict__ S,
    const float* __restrict__ Wq, const float* __restrict__ bq,
    const float* __restrict__ Wk, const float* __restrict__ bk,
    const float* __restrict__ Wv, const float* __restrict__ bv,
    uint16_t* __restrict__ Qp, uint16_t* __restrict__ Kp,
    uint16_t* __restrict__ Vp) {
    __shared__ char XsH[64 * 64];
    __shared__ char XsL[64 * 64];
    __shared__ float Bz[64 * 68];

    int bi = blockIdx.x;
    int proj = bi >> 10;
    int rem = bi & 1023;
    int b = rem >> 8;
    int dt = (rem >> 6) & 3;
    int nt = rem & 63;
    int d0 = dt * 64, n0 = nt * 64;

    int t = threadIdx.x;
    int lane = t & 63, wv = t >> 6;
    int g = lane >> 4, li = lane & 15;

    const float* X = (proj == 0 ? Y : S) + (size_t)b * CC * NN;
    const float* W = proj == 0 ? Wq : (proj == 1 ? Wk : Wv);
    const float* bias = proj == 0 ? bq : (proj == 1 ? bk : bv);

    f32x4 acc[4];
#pragma unroll
    for (int i = 0; i < 4; ++i) acc[i] = (f32x4){0.f, 0.f, 0.f, 0.f};

    int nloc = t & 63;
    int cq = t >> 6;
    uint32_t spch = (uint32_t)(cq ^ ((nloc >> 1) & 3));
    uint32_t rpch = (uint32_t)(g ^ ((li >> 1) & 3));

    for (int kk = 0; kk < 8; ++kk) {
        int c0 = kk * 32;
        {
            const float* xp = X + (size_t)(c0 + cq * 8) * NN + n0 + nloc;
            float xv[8];
#pragma unroll
            for (int j = 0; j < 8; ++j) xv[j] = xp[(size_t)j * NN];
            u32x4 hw, lw;
#pragma unroll
            for (int w = 0; w < 4; ++w) {
                float x = xv[2 * w], y = xv[2 * w + 1];
                _Float16 hx = (_Float16)x, hy = (_Float16)y;
                hw[w] = packh(hx, hy);
                lw[w] = packh((_Float16)(x - (float)hx), (_Float16)(y - (float)hy));
            }
            *(u32x4*)(XsH + nloc * 64 + spch * 16) = hw;
            *(u32x4*)(XsL + nloc * 64 + spch * 16) = lw;
        }
        __syncthreads();
        const float* wr = W + (size_t)(d0 + wv * 16 + li) * CC + c0 + g * 8;
        float wvv[8];
        *(float4*)&wvv[0] = ((const float4*)wr)[0];
        *(float4*)&wvv[4] = ((const float4*)wr)[1];
        f16x8 wh, wl;
        split8h(wvv, wh, wl);
#pragma unroll
        for (int nf = 0; nf < 4; ++nf) {
            const char* bp = XsH + (nf * 16 + li) * 64 + rpch * 16;
            f16x8 xh = ldsh8(bp);
            f16x8 xl = ldsh8(XsL + (nf * 16 + li) * 64 + rpch * 16);
            acc[nf] = MFMAH(wh, xh, acc[nf]);
            acc[nf] = MFMAH(wh, xl, acc[nf]);
            acc[nf] = MFMAH(wl, xh, acc[nf]);
        }
        __syncthreads();
    }

    if (proj == 2) {
#pragma unroll
        for (int r = 0; r < 4; ++r) {
            int d = d0 + wv * 16 + g * 4 + r;
            float bs = bias[d];
#pragma unroll
            for (int nf = 0; nf < 4; ++nf) {
                int n = n0 + nf * 16 + li;
                float v = acc[nf][r] + bs;
                Vp[(size_t)(b * DD + d) * NN + n] = h2u((_Float16)v);
            }
        }
    } else {
        const float QSCALE = 0.0625f * 1.4426950408889634f;  // 1/16 * log2e
#pragma unroll
        for (int r = 0; r < 4; ++r) {
            int d = d0 + wv * 16 + g * 4 + r;
            float bs = bias[d];
            int jj = d & 63;
            float inv = exp2f((float)jj * -0.20762050593046f);  // 10000^(-jj/64)
#pragma unroll
            for (int nf = 0; nf < 4; ++nf) {
                int n = n0 + nf * 16 + li;
                float v = acc[nf][r] + bs;
                float pos = (d < 128) ? (float)(n & 63) : (float)(n >> 6);
                float ar = pos * inv;
                v += (d & 64) ? cosf(ar) : sinf(ar);
                if (proj == 0) v *= QSCALE;
                Bz[(nf * 16 + li) * 68 + wv * 16 + g * 4 + r] = v;
            }
        }
        __syncthreads();
        {
            int nl = t >> 2;
            int dk = (t & 3) * 16;
            float vv[16];
#pragma unroll
            for (int q = 0; q < 4; ++q)
                *(float4*)&vv[q * 4] = *(const float4*)&Bz[nl * 68 + dk + q * 4];
            u32x4 w0, w1;
#pragma unroll
            for (int w = 0; w < 4; ++w)
                w0[w] = packh((_Float16)vv[2 * w], (_Float16)vv[2 * w + 1]);
#pragma unroll
            for (int w = 0; w < 4; ++w)
                w1[w] = packh((_Float16)vv[8 + 2 * w], (_Float16)vv[9 + 2 * w]);
            uint16_t* Ph = (proj == 0) ? Qp : Kp;
            size_t o = (size_t)(b * NN + n0 + nl) * DD + d0 + dk;
            ((u32x4*)(Ph + o))[0] = w0;
            ((u32x4*)(Ph + o))[1] = w1;
        }
    }
}

// ---------------------------------------------------------------------------
// Kernel 2: flash attention, 8 waves (qf = wv&3, m-half h = wv>>2).
// LDS: K slots @0/@32768, V slots @65536/@98304, P @131072 (8x2KB),
// m/l exchange @147456 (2KB). Total 149504.
// ---------------------------------------------------------------------------
__global__ __launch_bounds__(512, 2) void attn_kernel(
    const uint16_t* __restrict__ Qp, const uint16_t* __restrict__ Kp,
    const uint16_t* __restrict__ Vp,
    const float* __restrict__ Wo, const float* __restrict__ bo,
    float* __restrict__ Out) {
    extern __shared__ char smem[];

    int t = threadIdx.x;
    int lane = t & 63, wv = t >> 6;
    int g = lane >> 4, li = lane & 15;
    int qf = wv & 3, h = wv >> 2;

    int orig = ((blockIdx.x & 7) << 5) + (blockIdx.x >> 3);
    int b = orig >> 6;
    int nt = orig & 63;
    int n0 = nt * 64;

    // ---- Q fragments (B-operand: col q = li, k = g*8.. within kf*32)
    f16x8 qh[8];
    {
        size_t qrow = (size_t)(b * NN + n0 + qf * 16 + li) * DD;
#pragma unroll
        for (int kf = 0; kf < 8; ++kf)
            qh[kf] =
                __builtin_bit_cast(f16x8, *(const u32x4*)(Qp + qrow + kf * 32 + g * 8));
    }

    // ---- staging: waves 0-3 stage K (16 m-rows each), waves 4-7 stage V
    // (64 d-rows each). 8 x 1KB global_load_lds per wave per tile.
    const uint16_t* splane;
    uint32_t dstbase, adv;
    uint32_t soff[8];
    if (wv < 4) {
        splane = Kp + (size_t)b * NN * DD;
        dstbase = (uint32_t)wv * 8192u;
        adv = 64 * 256;
#pragma unroll
        for (int i = 0; i < 8; ++i) {
            int rr = wv * 16 + 2 * i + (lane >> 5);
            int cc = lane & 31;
            soff[i] = (uint32_t)(rr * 256 + ((cc ^ (rr & 7)) * 8));
        }
    } else {
        splane = Vp + (size_t)b * DD * NN;
        dstbase = 65536u + (uint32_t)(wv - 4) * 8192u;
        adv = 64;
#pragma unroll
        for (int i = 0; i < 8; ++i) {
            int rr = (wv - 4) * 64 + i * 8 + (lane >> 3);
            int cc = lane & 7;
            soff[i] = (uint32_t)rr * 4096u + (uint32_t)((cc ^ (rr & 7)) * 8);
        }
    }

    // ---- hoisted LDS addresses
    uint32_t PB = 131072u + (uint32_t)wv * 2048u;
    uint32_t ka[8];  // K read: row = h*32 + mf*16 + li (row&7 == li&7)
#pragma unroll
    for (int kf = 0; kf < 8; ++kf)
        ka[kf] = (uint32_t)(h * 32 + li) * 512u +
                 (uint32_t)(((kf * 4 + g) ^ (li & 7)) * 16);
    // V read: row d = df*16 + li, chunk = (h*4+g) ^ (li&7)
    uint32_t va = 65536u + (uint32_t)li * 128u +
                  (uint32_t)(((h * 4 + g) ^ (li & 7)) * 16);
    // P tile [16 q][32 m], row 128B, 16B-chunk XOR (li&7)
    uint32_t pw[2];
#pragma unroll
    for (int mf = 0; mf < 2; ++mf)
        pw[mf] = PB + (uint32_t)li * 128u +
                 (uint32_t)((((mf * 2 + (g >> 1))) ^ (li & 7)) * 16) +
                 (uint32_t)((g & 1) * 8);
    uint32_t pr = PB + (uint32_t)li * 128u + (uint32_t)((g ^ (li & 7)) * 16);

    f32x4 acc[16];  // O^T partial: col q = li, row d = df*16 + g*4 + r
#pragma unroll
    for (int i = 0; i < 16; ++i) acc[i] = (f32x4){0.f, 0.f, 0.f, 0.f};
    float mrun = -__builtin_inff();
    float lrun = 0.f;
    f32x4 stA[2], stB[2];

#define STAGEX(tt)                                                                      \
    do {                                                                                \
        uint32_t mo = (uint32_t)(tt)*adv;                                               \
        char* db = smem + (uint32_t)(((tt)&1) * 32768u) + dstbase;                      \
        _Pragma("unroll") for (int i = 0; i < 8; ++i) {                                 \
            __builtin_amdgcn_global_load_lds(                                           \
                (const __attribute__((address_space(1))) unsigned int*)(splane +        \
                                                                        soff[i] + mo),  \
                (__attribute__((address_space(3))) unsigned int*)(db + i * 1024), 16, 0,\
                0);                                                                     \
        }                                                                               \
    } while (0)

#define QKPART(T, SC)                                                                   \
    {                                                                                   \
        _Pragma("unroll") for (int mf = 0; mf < 2; ++mf) SC[mf] =                       \
            (f32x4){0.f, 0.f, 0.f, 0.f};                                                \
        __builtin_amdgcn_s_setprio(1);                                                  \
        _Pragma("unroll") for (int kf = 0; kf < 8; ++kf) {                              \
            _Pragma("unroll") for (int mf = 0; mf < 2; ++mf) {                          \
                f16x8 kfr = ldsh8(smem + ka[kf] +                                       \
                                  (uint32_t)(((T)&1) * 32768u + mf * 8192u));           \
                SC[mf] = MFMAH(kfr, qh[kf], SC[mf]);                                    \
            }                                                                           \
        }                                                                               \
        __builtin_amdgcn_s_setprio(0);                                                  \
    }

#define SMPV(T, SP)                                                                     \
    {                                                                                   \
        float sv[8];                                                                    \
        _Pragma("unroll") for (int mf = 0; mf < 2; ++mf)                                \
            _Pragma("unroll") for (int r = 0; r < 4; ++r) sv[mf * 4 + r] = SP[mf][r];   \
        float pm = sv[0];                                                               \
        _Pragma("unroll") for (int j = 1; j < 8; ++j) pm = fmaxf(pm, sv[j]);            \
        pm = fmaxf(pm, __shfl_xor(pm, 16));                                             \
        pm = fmaxf(pm, __shfl_xor(pm, 32));                                             \
        if (__any(pm > mrun + 5.77f)) {                                                 \
            float mnew = fmaxf(mrun, pm);                                               \
            float fac = exp2f(mrun - mnew);                                             \
            lrun *= fac;                                                                \
            _Pragma("unroll") for (int i2 = 0; i2 < 16; ++i2) {                         \
                acc[i2][0] *= fac; acc[i2][1] *= fac;                                   \
                acc[i2][2] *= fac; acc[i2][3] *= fac;                                   \
            }                                                                           \
            mrun = mnew;                                                                \
        }                                                                               \
        float p[8];                                                                     \
        float ps = 0.f;                                                                 \
        _Pragma("unroll") for (int j = 0; j < 8; ++j) {                                 \
            p[j] = exp2f(sv[j] - mrun);                                                 \
            ps += p[j];                                                                 \
        }                                                                               \
        uint32_t hw[4];                                                                 \
        _Pragma("unroll") for (int w = 0; w < 4; ++w) hw[w] = __builtin_bit_cast(       \
            uint32_t, __builtin_amdgcn_cvt_pkrtz(p[2 * w], p[2 * w + 1]));              \
        _Pragma("unroll") for (int mf = 0; mf < 2; ++mf) {                              \
            *(u32x2*)(smem + pw[mf]) = (u32x2){hw[2 * mf], hw[2 * mf + 1]};             \
        }                                                                               \
        ps += __shfl_xor(ps, 16);                                                       \
        ps += __shfl_xor(ps, 32);                                                       \
        lrun += ps;                                                                     \
        f16x8 pb = ldsh8(smem + pr);                                                    \
        __builtin_amdgcn_s_setprio(1);                                                  \
        _Pragma("unroll") for (int df = 0; df < 16; ++df) {                             \
            uint32_t vo = (uint32_t)((((T)&1) ? 0u : 32768u) + df * 2048u);             \
            f16x8 v0 = ldsh8(smem + va + vo);                                           \
            acc[df] = MFMAH(v0, pb, acc[df]);                                           \
        }                                                                               \
        __builtin_amdgcn_s_setprio(0);                                                  \
    }

#define ITER(T, SC, SP, DOSM, VMC)                                                      \
    {                                                                                   \
        asm volatile("s_waitcnt vmcnt(" #VMC ")" ::: "memory");                         \
        __builtin_amdgcn_s_barrier();                                                   \
        QKPART(T, SC);                                                                  \
        if (DOSM) SMPV(T, SP);                                                          \
        asm volatile("s_waitcnt lgkmcnt(0)" ::: "memory");                              \
        __builtin_amdgcn_s_barrier();                                                   \
        if (((T) < 62) && (wv < 4)) STAGEX((T) + 2);                                    \
        if (((T) < 63) && (wv >= 4)) STAGEX((T) + 1);                                   \
    }

    // prologue: K(0),K(1) by K-waves; V(0) by V-waves
    if (wv < 4) {
        STAGEX(0);
        STAGEX(1);
    } else {
        STAGEX(0);
    }

    ITER(0, stA, stB, 0, 8);
#pragma unroll 1
    for (int tp = 0; tp < 31; ++tp) {
        ITER(2 * tp + 1, stB, stA, 1, 8);
        ITER(2 * tp + 2, stA, stB, 1, 8);
    }
    ITER(63, stB, stA, 1, 0);
    SMPV(64, stB);  // tile 63 (V slot 1)

#undef ITER
#undef SMPV
#undef QKPART
#undef STAGEX

    // ---- flash-split combine: waves 4-7 publish (m,l,acc); 0-3 merge.
    __syncthreads();
    if (wv >= 4) {
        uint32_t wb = 65536u + (uint32_t)(wv - 4) * 16384u;
#pragma unroll
        for (int df = 0; df < 16; ++df)
            *(f32x4*)(smem + wb + (uint32_t)df * 1024u + (uint32_t)lane * 16u) =
                acc[df];
        *(float*)(smem + 147456u + (uint32_t)(wv - 4) * 512u + (uint32_t)lane * 8u) =
            mrun;
        *(float*)(smem + 147456u + (uint32_t)(wv - 4) * 512u + (uint32_t)lane * 8u +
                  4u) = lrun;
    }
    __syncthreads();

    if (wv < 4) {
        float m2 =
            *(const float*)(smem + 147456u + (uint32_t)wv * 512u + (uint32_t)lane * 8u);
        float l2 = *(const float*)(smem + 147456u + (uint32_t)wv * 512u +
                                   (uint32_t)lane * 8u + 4u);
        float mN = fmaxf(mrun, m2);
        float f1 = exp2f(mrun - mN);
        float f2 = exp2f(m2 - mN);
        float lm = lrun * f1 + l2 * f2;
        uint32_t wb = 65536u + (uint32_t)wv * 16384u;
#pragma unroll
        for (int df = 0; df < 16; ++df) {
            f32x4 a2 =
                *(const f32x4*)(smem + wb + (uint32_t)df * 1024u + (uint32_t)lane * 16u);
#pragma unroll
            for (int r = 0; r < 4; ++r) acc[df][r] = acc[df][r] * f1 + a2[r] * f2;
        }
        float rl = 1.0f / lm;
        // ---- normalize, bounce O^T -> LDS fp16 hi/lo [64 n][256 d] swizzled
        char* zh = smem;
        char* zl = smem + 32768;
        int n = qf * 16 + li;
#pragma unroll
        for (int df = 0; df < 16; ++df) {
#pragma unroll
            for (int rp = 0; rp < 2; ++rp) {
                float a0 = acc[df][2 * rp] * rl, a1 = acc[df][2 * rp + 1] * rl;
                _Float16 h0 = (_Float16)a0, h1 = (_Float16)a1;
                uint32_t whi = packh(h0, h1);
                uint32_t wlo =
                    packh((_Float16)(a0 - (float)h0), (_Float16)(a1 - (float)h1));
                uint32_t chunk = (uint32_t)((df * 2 + (g >> 1)) ^ (li & 7));
                uint32_t off = (uint32_t)n * 512 + chunk * 16 + (g & 1) * 8 + rp * 4;
                *(uint32_t*)(zh + off) = whi;
                *(uint32_t*)(zl + off) = wlo;
            }
        }
    }
    __syncthreads();

    // ---- fused output projection: 8 waves, 32 cs each
    const char* zh = smem;
    const char* zl = smem + 32768;
    f32x4 oc[2][4];
#pragma unroll
    for (int i = 0; i < 2; ++i)
#pragma unroll
        for (int j = 0; j < 4; ++j) oc[i][j] = (f32x4){0.f, 0.f, 0.f, 0.f};
    int cs0 = wv * 32;
#pragma unroll 1
    for (int kf = 0; kf < 8; ++kf) {
        f16x8 zhv[4], zlv[4];
#pragma unroll
        for (int nf = 0; nf < 4; ++nf) {
            uint32_t off = (uint32_t)(nf * 16 + li) * 512 +
                           (uint32_t)((kf * 4 + g) ^ (li & 7)) * 16;
            zhv[nf] = ldsh8(zh + off);
            zlv[nf] = ldsh8(zl + off);
        }
#pragma unroll
        for (int csf = 0; csf < 2; ++csf) {
            const float* wr = Wo + (size_t)(cs0 + csf * 16 + li) * DD + kf * 32 + g * 8;
            float wvv[8];
            *(float4*)&wvv[0] = ((const float4*)wr)[0];
            *(float4*)&wvv[4] = ((const float4*)wr)[1];
            f16x8 wh, wl;
            split8h(wvv, wh, wl);
#pragma unroll
            for (int nf = 0; nf < 4; ++nf) {
                oc[csf][nf] = MFMAH(wh, zhv[nf], oc[csf][nf]);
                oc[csf][nf] = MFMAH(wh, zlv[nf], oc[csf][nf]);
                oc[csf][nf] = MFMAH(wl, zhv[nf], oc[csf][nf]);
            }
        }
    }
#pragma unroll
    for (int csf = 0; csf < 2; ++csf) {
#pragma unroll
        for (int r = 0; r < 4; ++r) {
            int cs = cs0 + csf * 16 + g * 4 + r;
            float bb = bo[cs];
#pragma unroll
            for (int nf = 0; nf < 4; ++nf)
                Out[(size_t)(b * 256 + cs) * NN + n0 + nf * 16 + li] =
                    oc[csf][nf][r] + bb;
        }
    }
}

// ---------------------------------------------------------------------------
extern "C" void kernel_launch(void* const* d_in, const int* in_sizes, int n_in,
                              void* d_out, int out_size, void* d_ws, size_t ws_size,
                              hipStream_t stream) {
    (void)in_sizes; (void)n_in; (void)out_size; (void)ws_size;
    const float* Y = (const float*)d_in[0];
    const float* S = (const float*)d_in[1];
    const float* Wq = (const float*)d_in[2];
    const float* bq = (const float*)d_in[3];
    const float* Wk = (const float*)d_in[4];
    const float* bk = (const float*)d_in[5];
    const float* Wv = (const float*)d_in[6];
    const float* bv = (const float*)d_in[7];
    const float* Wo = (const float*)d_in[8];
    const float* bo = (const float*)d_in[9];
    float* Out = (float*)d_out;

    uint16_t* ws = (uint16_t*)d_ws;
    uint16_t* Qp = ws + 0 * (size_t)PS;
    uint16_t* Kp = ws + 1 * (size_t)PS;
    uint16_t* Vp = ws + 2 * (size_t)PS;

    (void)hipFuncSetAttribute((const void*)attn_kernel,
                              hipFuncAttributeMaxDynamicSharedMemorySize, 149504);

    proj_kernel<<<3072, 256, 0, stream>>>(Y, S, Wq, bq, Wk, bk, Wv, bv, Qp, Kp, Vp);
    attn_kernel<<<256, 512, 149504, stream>>>(Qp, Kp, Vp, Wo, bo, Out);
}